// Round 10
// baseline (292.199 us; speedup 1.0000x reference)
//
#include <hip/hip_runtime.h>
#include <math.h>

#define BB 4
#define CC 256
#define DD 32
#define NN 4096

typedef __attribute__((ext_vector_type(8))) short short8;
typedef __attribute__((ext_vector_type(4))) short short4v;
typedef __attribute__((ext_vector_type(4))) float floatx4;
typedef __attribute__((ext_vector_type(4))) int intx4;
typedef __attribute__((ext_vector_type(2))) int intx2;

#define SCALEF (0.17677669529663687f * 1.4426950408889634f)  // 1/sqrt(32)*log2(e)

// float -> bf16 round-to-nearest-even
__device__ __forceinline__ ushort f2bf(float f) {
    unsigned int u = __builtin_bit_cast(unsigned int, f);
    u += 0x7FFFu + ((u >> 16) & 1u);
    return (ushort)(u >> 16);
}
// pack two floats' bf16 truncations into one dword with a single v_perm_b32
__device__ __forceinline__ int pk_trunc(float a, float b) {
    return (int)__builtin_amdgcn_perm(__builtin_bit_cast(unsigned, b),
                                      __builtin_bit_cast(unsigned, a),
                                      0x07060302u);
}
__device__ __forceinline__ float fast_exp2(float x) {
#if __has_builtin(__builtin_amdgcn_exp2f)
    return __builtin_amdgcn_exp2f(x);
#else
    return exp2f(x);
#endif
}

// K=16 bf16 MFMA: B-operand layout (k=qd*4+j, n=l15) == C-layout of the
// K=32 S-MFMA (row=qd*4+r, col=l15)  ->  exp(S) needs NO cross-lane relayout.
__device__ __forceinline__ floatx4 mfma16bf(short4v a, short4v b, floatx4 c) {
#if __has_builtin(__builtin_amdgcn_mfma_f32_16x16x16_bf16)
    return __builtin_amdgcn_mfma_f32_16x16x16_bf16(a, b, c, 0, 0, 0);
#elif __has_builtin(__builtin_amdgcn_mfma_f32_16x16x16bf16_1k)
    return __builtin_amdgcn_mfma_f32_16x16x16bf16_1k(a, b, c, 0, 0, 0);
#else
    floatx4 d;
    asm("v_mfma_f32_16x16x16_bf16 %0, %1, %2, %3"
        : "=v"(d) : "v"(a), "v"(b), "0"(c));
    return d;
#endif
}

// ---------------------------------------------------------------------------
// Kernel 1: MFMA QKV projection (R6/R9 version — unchanged).
// Wave tile = 64o x 32n; 2560 waves.  Outputs bf16: qb,kb (B,N,32)
// (q pre-scaled by 1/sqrt(32)*log2(e)), vb (B,C,N).
// ---------------------------------------------------------------------------
__global__ __launch_bounds__(256) void qkv_mfma(
    const float* __restrict__ x,
    const float* __restrict__ Wq, const float* __restrict__ bq,
    const float* __restrict__ Wk, const float* __restrict__ bk,
    const float* __restrict__ Wv, const float* __restrict__ bv,
    ushort* __restrict__ qb, ushort* __restrict__ kb, ushort* __restrict__ vb)
{
    const int t = threadIdx.x;
    const int wave = t >> 6;
    const int lane = t & 63;
    const int l15 = lane & 15, qd = lane >> 4;
    const int b = blockIdx.z, m0 = blockIdx.y * 64;
    const int n0 = blockIdx.x * 128 + wave * 32;
    const float* xb = x + (size_t)b * CC * NN;
    const bool isqk = (m0 == 0);

    const float* wr[4];
    if (isqk) {
        wr[0] = Wq + (size_t)l15 * CC;
        wr[1] = Wq + (size_t)(16 + l15) * CC;
        wr[2] = Wk + (size_t)l15 * CC;
        wr[3] = Wk + (size_t)(16 + l15) * CC;
    } else {
        #pragma unroll
        for (int f = 0; f < 4; ++f) wr[f] = Wv + (size_t)(m0 - 64 + f * 16 + l15) * CC;
    }

    floatx4 z = {0.f, 0.f, 0.f, 0.f};
    floatx4 acc[4][2];
    #pragma unroll
    for (int i = 0; i < 4; ++i) { acc[i][0] = z; acc[i][1] = z; }

    for (int k0 = 0; k0 < CC; k0 += 32) {
        short8 af[4], bf[2];
        #pragma unroll
        for (int f = 0; f < 4; ++f) {
            const float* p = wr[f] + k0 + qd * 8;
            float w[8];
            #pragma unroll
            for (int j = 0; j < 8; ++j) w[j] = p[j];
            if (isqk && f < 2) {
                #pragma unroll
                for (int j = 0; j < 8; ++j) w[j] *= SCALEF;
            }
            intx4 d;
            d[0] = pk_trunc(w[0], w[1]); d[1] = pk_trunc(w[2], w[3]);
            d[2] = pk_trunc(w[4], w[5]); d[3] = pk_trunc(w[6], w[7]);
            af[f] = __builtin_bit_cast(short8, d);
        }
        #pragma unroll
        for (int f = 0; f < 2; ++f) {
            const float* p = xb + (size_t)(k0 + qd * 8) * NN + n0 + f * 16 + l15;
            float xv[8];
            #pragma unroll
            for (int j = 0; j < 8; ++j) xv[j] = p[(size_t)j * NN];
            intx4 d;
            d[0] = pk_trunc(xv[0], xv[1]); d[1] = pk_trunc(xv[2], xv[3]);
            d[2] = pk_trunc(xv[4], xv[5]); d[3] = pk_trunc(xv[6], xv[7]);
            bf[f] = __builtin_bit_cast(short8, d);
        }
        #pragma unroll
        for (int fm = 0; fm < 4; ++fm)
            #pragma unroll
            for (int fn = 0; fn < 2; ++fn)
                acc[fm][fn] = __builtin_amdgcn_mfma_f32_16x16x32_bf16(af[fm], bf[fn], acc[fm][fn], 0, 0, 0);
    }

    #pragma unroll
    for (int fm = 0; fm < 4; ++fm) {
        #pragma unroll
        for (int r = 0; r < 4; ++r) {
            int o = m0 + fm * 16 + qd * 4 + r;
            if (isqk) {
                if (fm < 2) {
                    float bo = bq[o] * SCALEF;
                    #pragma unroll
                    for (int fn = 0; fn < 2; ++fn)
                        qb[((size_t)b * NN + n0 + fn * 16 + l15) * DD + o] = f2bf(acc[fm][fn][r] + bo);
                } else {
                    float bo = bk[o - 32];
                    #pragma unroll
                    for (int fn = 0; fn < 2; ++fn)
                        kb[((size_t)b * NN + n0 + fn * 16 + l15) * DD + (o - 32)] = f2bf(acc[fm][fn][r] + bo);
                }
            } else {
                float bo = bv[o - 64];
                #pragma unroll
                for (int fn = 0; fn < 2; ++fn)
                    vb[((size_t)b * CC + (o - 64)) * NN + n0 + fn * 16 + l15] = f2bf(acc[fm][fn][r] + bo);
            }
        }
    }
}

// ---------------------------------------------------------------------------
// Kernel 2: MFMA flash attention, R6 shape (best measured: 4096 waves) with
// the K=16 no-shuffle P-path.  Block = 4 waves = 4 key-quarters of one
// (64-q tile, 64-ch group); wave = 64q x 64ch over 1024 keys (32 tiles).
// Per tile per f: S = 2x mfma 16x16x32 (C-layout row=qd*4+r=key, col=q);
// exp2 -> pack 4 bf16/lane -> that IS the 16x16x16 B-operand fragment.
// PV: 8x mfma 16x16x16 (V A-frags = short4 from (C,N)); l: 2x ones-MFMA.
// Zero ds_bpermute / cndmask in the loop.  Partial O/l additive; 3-barrier
// LDS tree.  Grid (8,32,4): x = XCD slot, b = slot/2 pins batch K/V to L2.
// ---------------------------------------------------------------------------
__global__ __launch_bounds__(256) void attn_mfma(
    const ushort* __restrict__ qb, const ushort* __restrict__ kb,
    const ushort* __restrict__ vb, ushort* __restrict__ aoT)
{
    __shared__ float red[2][4096];   // [slot][((f*4+ct)*4+r)*64 + lane] = 32 KB
    __shared__ float lredN[4][64];   // [wave][q]

    const int t = threadIdx.x;
    const int kh = t >> 6;               // key-quarter 0..3
    const int lane = t & 63;
    const int l15 = lane & 15;
    const int qd = lane >> 4;
    const int slot = blockIdx.x;         // ~XCD id (round-robin heuristic)
    const int b = slot >> 1;             // 2 XCDs per batch
    const int qt = (slot & 1) * 32 + blockIdx.y;
    const int q0 = qt * 64;
    const int c0 = blockIdx.z * 64;

    const ushort* krow = kb + ((size_t)b * NN + kh * 1024 + l15) * DD + qd * 8;
    const ushort* vrow[4];
    #pragma unroll
    for (int ct = 0; ct < 4; ++ct)
        vrow[ct] = vb + ((size_t)b * CC + c0 + ct * 16 + l15) * (size_t)NN + kh * 1024 + qd * 4;

    short8 qf[4];
    #pragma unroll
    for (int f = 0; f < 4; ++f)
        qf[f] = *(const short8*)(qb + ((size_t)b * NN + q0 + f * 16 + l15) * DD + qd * 8);

    const short4v ones4 = {0x3F80, 0x3F80, 0x3F80, 0x3F80};

    floatx4 z = {0.f, 0.f, 0.f, 0.f};
    floatx4 acc[4][4];   // [qfrag][chfrag]
    floatx4 accl[4];
    #pragma unroll
    for (int f = 0; f < 4; ++f) {
        accl[f] = z;
        #pragma unroll
        for (int c = 0; c < 4; ++c) acc[f][c] = z;
    }

    for (int kt = 0; kt < 32; ++kt) {
        short8 kf0 = *(const short8*)(krow);
        short8 kf1 = *(const short8*)(krow + 16 * DD);
        short4v vf0[4], vf1[4];
        #pragma unroll
        for (int ct = 0; ct < 4; ++ct) {
            vf0[ct] = *(const short4v*)(vrow[ct]);
            vf1[ct] = *(const short4v*)(vrow[ct] + 16);
        }
        krow += 32 * DD;
        #pragma unroll
        for (int ct = 0; ct < 4; ++ct) vrow[ct] += 32;

        #pragma unroll
        for (int f = 0; f < 4; ++f) {
            floatx4 s0 = __builtin_amdgcn_mfma_f32_16x16x32_bf16(kf0, qf[f], z, 0, 0, 0);
            floatx4 s1 = __builtin_amdgcn_mfma_f32_16x16x32_bf16(kf1, qf[f], z, 0, 0, 0);

            float e00 = fast_exp2(s0[0]), e01 = fast_exp2(s0[1]);
            float e02 = fast_exp2(s0[2]), e03 = fast_exp2(s0[3]);
            float e10 = fast_exp2(s1[0]), e11 = fast_exp2(s1[1]);
            float e12 = fast_exp2(s1[2]), e13 = fast_exp2(s1[3]);

            intx2 p0d, p1d;
            p0d[0] = pk_trunc(e00, e01); p0d[1] = pk_trunc(e02, e03);
            p1d[0] = pk_trunc(e10, e11); p1d[1] = pk_trunc(e12, e13);
            short4v pt0 = __builtin_bit_cast(short4v, p0d);
            short4v pt1 = __builtin_bit_cast(short4v, p1d);

            accl[f] = mfma16bf(ones4, pt0, accl[f]);
            accl[f] = mfma16bf(ones4, pt1, accl[f]);

            #pragma unroll
            for (int ct = 0; ct < 4; ++ct) {
                acc[f][ct] = mfma16bf(vf0[ct], pt0, acc[f][ct]);
                acc[f][ct] = mfma16bf(vf1[ct], pt1, acc[f][ct]);
            }
        }
    }

    float lsum[4];
    #pragma unroll
    for (int f = 0; f < 4; ++f) lsum[f] = accl[f][0];

    // publish l partials (before the tree's first barrier; consumed after last)
    if (qd == 0)
        #pragma unroll
        for (int f = 0; f < 4; ++f) lredN[kh][f * 16 + l15] = lsum[f];

    // ---- O reduction tree over key-quarters: (0+=1, 2+=3), then 0+=2 ----
    if (kh & 1) {
        const int s = kh >> 1;
        #pragma unroll
        for (int f = 0; f < 4; ++f)
            #pragma unroll
            for (int ct = 0; ct < 4; ++ct)
                #pragma unroll
                for (int r = 0; r < 4; ++r)
                    red[s][((f * 4 + ct) * 4 + r) * 64 + lane] = acc[f][ct][r];
    }
    __syncthreads();
    if (!(kh & 1)) {
        const int s = kh >> 1;
        #pragma unroll
        for (int f = 0; f < 4; ++f)
            #pragma unroll
            for (int ct = 0; ct < 4; ++ct)
                #pragma unroll
                for (int r = 0; r < 4; ++r)
                    acc[f][ct][r] += red[s][((f * 4 + ct) * 4 + r) * 64 + lane];
    }
    __syncthreads();
    if (kh == 2) {
        #pragma unroll
        for (int f = 0; f < 4; ++f)
            #pragma unroll
            for (int ct = 0; ct < 4; ++ct)
                #pragma unroll
                for (int r = 0; r < 4; ++r)
                    red[0][((f * 4 + ct) * 4 + r) * 64 + lane] = acc[f][ct][r];
    }
    __syncthreads();
    if (kh == 0) {
        #pragma unroll
        for (int f = 0; f < 4; ++f)
            #pragma unroll
            for (int ct = 0; ct < 4; ++ct)
                #pragma unroll
                for (int r = 0; r < 4; ++r)
                    acc[f][ct][r] += red[0][((f * 4 + ct) * 4 + r) * 64 + lane];
        #pragma unroll
        for (int f = 0; f < 4; ++f) {
            const float l = lredN[0][f * 16 + l15] + lredN[1][f * 16 + l15]
                          + lredN[2][f * 16 + l15] + lredN[3][f * 16 + l15];
            const float inv = 1.0f / l;
            ushort* dst = aoT + ((size_t)b * NN + q0 + f * 16 + l15) * CC + c0 + qd * 4;
            #pragma unroll
            for (int ct = 0; ct < 4; ++ct) {
                ushort4 h;
                h.x = f2bf(acc[f][ct][0] * inv);
                h.y = f2bf(acc[f][ct][1] * inv);
                h.z = f2bf(acc[f][ct][2] * inv);
                h.w = f2bf(acc[f][ct][3] * inv);
                *(ushort4*)(dst + ct * 16) = h;
            }
        }
    }
}

// ---------------------------------------------------------------------------
// Kernel 3: MFMA output projection + residual (R9 version — unchanged).
// Wave tile = 64m x 32n -> 512 blocks (2/CU).  out = x + gamma*(Wp@ao + bp).
// ---------------------------------------------------------------------------
__global__ __launch_bounds__(256) void proj_mfma(
    const ushort* __restrict__ aoT, const float* __restrict__ Wp,
    const float* __restrict__ bp, const float* __restrict__ x,
    const float* __restrict__ gamma, float* __restrict__ out)
{
    const int t = threadIdx.x;
    const int wave = t >> 6;
    const int lane = t & 63;
    const int l15 = lane & 15;
    const int qd = lane >> 4;
    const int b = blockIdx.z;
    const int m0 = blockIdx.y * 64;
    const int n0 = blockIdx.x * 128 + wave * 32;

    floatx4 z = {0.f, 0.f, 0.f, 0.f};
    floatx4 acc[4][2];   // [fm][fn]
    #pragma unroll
    for (int i = 0; i < 4; ++i) { acc[i][0] = z; acc[i][1] = z; }

    const ushort* arow = aoT + ((size_t)b * NN + n0 + l15) * CC + qd * 8;
    const float* wrow = Wp + (size_t)(m0 + l15) * CC + qd * 8;

    #pragma unroll
    for (int k0 = 0; k0 < CC; k0 += 32) {
        short8 af[4], bf[2];
        #pragma unroll
        for (int f = 0; f < 4; ++f) {
            const float* p = wrow + (size_t)f * 16 * CC + k0;
            intx4 d;
            d[0] = pk_trunc(p[0], p[1]); d[1] = pk_trunc(p[2], p[3]);
            d[2] = pk_trunc(p[4], p[5]); d[3] = pk_trunc(p[6], p[7]);
            af[f] = __builtin_bit_cast(short8, d);
        }
        #pragma unroll
        for (int f = 0; f < 2; ++f)
            bf[f] = *(const short8*)(arow + (size_t)f * 16 * CC + k0);
        #pragma unroll
        for (int fm = 0; fm < 4; ++fm)
            #pragma unroll
            for (int fn = 0; fn < 2; ++fn)
                acc[fm][fn] = __builtin_amdgcn_mfma_f32_16x16x32_bf16(af[fm], bf[fn], acc[fm][fn], 0, 0, 0);
    }

    const float g = gamma[0];
    #pragma unroll
    for (int fm = 0; fm < 4; ++fm) {
        #pragma unroll
        for (int r = 0; r < 4; ++r) {
            int m = m0 + fm * 16 + qd * 4 + r;
            float bpv = bp[m];
            #pragma unroll
            for (int fn = 0; fn < 2; ++fn) {
                size_t addr = ((size_t)b * CC + m) * NN + n0 + fn * 16 + l15;
                out[addr] = fmaf(g, acc[fm][fn][r] + bpv, x[addr]);
            }
        }
    }
}

extern "C" void kernel_launch(void* const* d_in, const int* in_sizes, int n_in,
                              void* d_out, int out_size, void* d_ws, size_t ws_size,
                              hipStream_t stream)
{
    const float* x     = (const float*)d_in[0];
    const float* Wq    = (const float*)d_in[1];
    const float* bq    = (const float*)d_in[2];
    const float* Wk    = (const float*)d_in[3];
    const float* bk    = (const float*)d_in[4];
    const float* Wv    = (const float*)d_in[5];
    const float* bv    = (const float*)d_in[6];
    const float* Wp    = (const float*)d_in[7];
    const float* bp    = (const float*)d_in[8];
    const float* gamma = (const float*)d_in[9];
    float* out = (float*)d_out;

    ushort* qbw = (ushort*)d_ws;                        // B*N*32  bf16 = 1 MB
    ushort* kbw = qbw + (size_t)BB * NN * DD;           // B*N*32  bf16 = 1 MB
    ushort* vbw = kbw + (size_t)BB * NN * DD;           // B*C*N   bf16 = 8 MB
    ushort* aoT = vbw + (size_t)BB * CC * NN;           // B*N*C   bf16 = 8 MB

    qkv_mfma<<<dim3(NN / 128, 5, BB), 256, 0, stream>>>(x, Wq, bq, Wk, bk, Wv, bv, qbw, kbw, vbw);
    attn_mfma<<<dim3(8, 32, 4), 256, 0, stream>>>(qbw, kbw, vbw, aoT);
    proj_mfma<<<dim3(NN / 128, CC / 64, BB), 256, 0, stream>>>(aoT, Wp, bp, x, gamma, out);
}

// Round 11
// 224.575 us; speedup vs baseline: 1.3011x; 1.3011x over previous
//
#include <hip/hip_runtime.h>
#include <math.h>

#define BB 4
#define CC 256
#define DD 32
#define NN 4096

typedef __attribute__((ext_vector_type(8))) short short8;
typedef __attribute__((ext_vector_type(4))) float floatx4;
typedef __attribute__((ext_vector_type(4))) int intx4;

#define SCALEF (0.17677669529663687f * 1.4426950408889634f)  // 1/sqrt(32)*log2(e)

// float -> bf16 round-to-nearest-even
__device__ __forceinline__ ushort f2bf(float f) {
    unsigned int u = __builtin_bit_cast(unsigned int, f);
    u += 0x7FFFu + ((u >> 16) & 1u);
    return (ushort)(u >> 16);
}
// pack two floats' bf16 truncations into one dword with a single v_perm_b32
__device__ __forceinline__ int pk_trunc(float a, float b) {
    return (int)__builtin_amdgcn_perm(__builtin_bit_cast(unsigned, b),
                                      __builtin_bit_cast(unsigned, a),
                                      0x07060302u);
}
__device__ __forceinline__ float fast_exp2(float x) {
#if __has_builtin(__builtin_amdgcn_exp2f)
    return __builtin_amdgcn_exp2f(x);
#else
    return exp2f(x);
#endif
}

// ---------------------------------------------------------------------------
// Kernel 1: MFMA QKV projection, high-TLP variant.  Wave tile = 32o x 32n
// (acc 16 VGPRs) -> 5120 waves = 5/SIMD.  m-tile of 32 aligns with the
// q/k/v row split: mt==0 -> Wq (scaled), mt==1 -> Wk, mt>=2 -> Wv rows
// (mt-2)*32.. — output branch is block-uniform.  A-frags: fp32 W rows +
// v_perm pack (L2-hot).  B-frags: 8 coalesced-across-l15 fp32 x loads
// (stride N) + pack.  Outputs bf16: qb,kb (B,N,32), vb (B,C,N).
// ---------------------------------------------------------------------------
__global__ __launch_bounds__(256) void qkv_mfma(
    const float* __restrict__ x,
    const float* __restrict__ Wq, const float* __restrict__ bq,
    const float* __restrict__ Wk, const float* __restrict__ bk,
    const float* __restrict__ Wv, const float* __restrict__ bv,
    ushort* __restrict__ qb, ushort* __restrict__ kb, ushort* __restrict__ vb)
{
    const int t = threadIdx.x;
    const int wave = t >> 6;
    const int lane = t & 63;
    const int l15 = lane & 15, qd = lane >> 4;
    const int b = blockIdx.z, mt = blockIdx.y;   // mt 0..9
    const int n0 = blockIdx.x * 128 + wave * 32;
    const float* xb = x + (size_t)b * CC * NN;

    const float* wr[2];
    if (mt == 0) {
        wr[0] = Wq + (size_t)l15 * CC;
        wr[1] = Wq + (size_t)(16 + l15) * CC;
    } else if (mt == 1) {
        wr[0] = Wk + (size_t)l15 * CC;
        wr[1] = Wk + (size_t)(16 + l15) * CC;
    } else {
        wr[0] = Wv + (size_t)((mt - 2) * 32 + l15) * CC;
        wr[1] = Wv + (size_t)((mt - 2) * 32 + 16 + l15) * CC;
    }

    floatx4 z = {0.f, 0.f, 0.f, 0.f};
    floatx4 acc[2][2];
    acc[0][0] = z; acc[0][1] = z; acc[1][0] = z; acc[1][1] = z;

    for (int k0 = 0; k0 < CC; k0 += 32) {
        short8 af[2], bf[2];
        #pragma unroll
        for (int f = 0; f < 2; ++f) {
            const float* p = wr[f] + k0 + qd * 8;
            float w[8];
            #pragma unroll
            for (int j = 0; j < 8; ++j) w[j] = p[j];
            if (mt == 0) {
                #pragma unroll
                for (int j = 0; j < 8; ++j) w[j] *= SCALEF;
            }
            intx4 d;
            d[0] = pk_trunc(w[0], w[1]); d[1] = pk_trunc(w[2], w[3]);
            d[2] = pk_trunc(w[4], w[5]); d[3] = pk_trunc(w[6], w[7]);
            af[f] = __builtin_bit_cast(short8, d);
        }
        #pragma unroll
        for (int f = 0; f < 2; ++f) {
            const float* p = xb + (size_t)(k0 + qd * 8) * NN + n0 + f * 16 + l15;
            float xv[8];
            #pragma unroll
            for (int j = 0; j < 8; ++j) xv[j] = p[(size_t)j * NN];
            intx4 d;
            d[0] = pk_trunc(xv[0], xv[1]); d[1] = pk_trunc(xv[2], xv[3]);
            d[2] = pk_trunc(xv[4], xv[5]); d[3] = pk_trunc(xv[6], xv[7]);
            bf[f] = __builtin_bit_cast(short8, d);
        }
        #pragma unroll
        for (int fm = 0; fm < 2; ++fm)
            #pragma unroll
            for (int fn = 0; fn < 2; ++fn)
                acc[fm][fn] = __builtin_amdgcn_mfma_f32_16x16x32_bf16(af[fm], bf[fn], acc[fm][fn], 0, 0, 0);
    }

    #pragma unroll
    for (int fm = 0; fm < 2; ++fm) {
        #pragma unroll
        for (int r = 0; r < 4; ++r) {
            const int o = fm * 16 + qd * 4 + r;      // row within this 32-block
            if (mt == 0) {
                float bo = bq[o] * SCALEF;
                #pragma unroll
                for (int fn = 0; fn < 2; ++fn)
                    qb[((size_t)b * NN + n0 + fn * 16 + l15) * DD + o] = f2bf(acc[fm][fn][r] + bo);
            } else if (mt == 1) {
                float bo = bk[o];
                #pragma unroll
                for (int fn = 0; fn < 2; ++fn)
                    kb[((size_t)b * NN + n0 + fn * 16 + l15) * DD + o] = f2bf(acc[fm][fn][r] + bo);
            } else {
                const int oc = (mt - 2) * 32 + o;
                float bo = bv[oc];
                #pragma unroll
                for (int fn = 0; fn < 2; ++fn)
                    vb[((size_t)b * CC + oc) * NN + n0 + fn * 16 + l15] = f2bf(acc[fm][fn][r] + bo);
            }
        }
    }
}

// ---------------------------------------------------------------------------
// Kernel 2: MFMA flash attention — R6 version VERBATIM (best measured:
// 102 µs; R7/R8/R9/R10 structural variants all regressed).  Block = 4 waves
// = 4 key-quarters of one (64-q tile, 64-ch group); wave = 64q x 64ch over
// 1024 keys.  Partial O/l additive (no max-subtraction), 3-barrier LDS tree.
// Grid (8,32,4): x = XCD slot, b = slot/2 pins each batch's K/V to 2 XCDs.
// ---------------------------------------------------------------------------
__global__ __launch_bounds__(256) void attn_mfma(
    const ushort* __restrict__ qb, const ushort* __restrict__ kb,
    const ushort* __restrict__ vb, ushort* __restrict__ aoT)
{
    __shared__ float red[2][4096];   // [slot][((f*4+ct)*4+r)*64 + lane]
    __shared__ float lred[2][64];    // [slot][f*16 + q]

    const int t = threadIdx.x;
    const int kh = t >> 6;               // key-quarter 0..3
    const int lane = t & 63;
    const int l15 = lane & 15;
    const int qd = lane >> 4;
    const int slot = blockIdx.x;         // ~XCD id (round-robin heuristic)
    const int b = slot >> 1;             // 2 XCDs per batch
    const int qt = (slot & 1) * 32 + blockIdx.y;
    const int q0 = qt * 64;
    const int c0 = blockIdx.z * 64;

    const ushort* krow = kb + ((size_t)b * NN + kh * 1024 + l15) * DD + qd * 8;
    const ushort* vrow = vb + ((size_t)b * CC + c0 + l15) * (size_t)NN + kh * 1024 + qd * 8;

    short8 qf[4];
    #pragma unroll
    for (int f = 0; f < 4; ++f)
        qf[f] = *(const short8*)(qb + ((size_t)b * NN + q0 + f * 16 + l15) * DD + qd * 8);

    const short8 ones = {0x3F80, 0x3F80, 0x3F80, 0x3F80, 0x3F80, 0x3F80, 0x3F80, 0x3F80};

    floatx4 z = {0.f, 0.f, 0.f, 0.f};
    floatx4 acc[4][4];   // [qfrag][chfrag]
    floatx4 accl[4];
    #pragma unroll
    for (int f = 0; f < 4; ++f) {
        accl[f] = z;
        #pragma unroll
        for (int c = 0; c < 4; ++c) acc[f][c] = z;
    }

    const int base  = (qd & 1) * 32 + l15;   // proven transpose lane mapping
    const int base2 = base + 16;
    const bool hi = (lane >= 32);

    for (int kt = 0; kt < 32; ++kt) {
        short8 kf0 = *(const short8*)(krow);
        short8 kf1 = *(const short8*)(krow + 16 * DD);
        short8 vf[4];
        #pragma unroll
        for (int ct = 0; ct < 4; ++ct)
            vf[ct] = *(const short8*)(vrow + (size_t)ct * 16 * NN);
        krow += 32 * DD;
        vrow += 32;

        short8 pt[4];
        #pragma unroll
        for (int f = 0; f < 4; ++f) {
            floatx4 s0 = __builtin_amdgcn_mfma_f32_16x16x32_bf16(kf0, qf[f], z, 0, 0, 0);
            floatx4 s1 = __builtin_amdgcn_mfma_f32_16x16x32_bf16(kf1, qf[f], z, 0, 0, 0);

            float e00 = fast_exp2(s0[0]), e01 = fast_exp2(s0[1]);
            float e02 = fast_exp2(s0[2]), e03 = fast_exp2(s0[3]);
            float e10 = fast_exp2(s1[0]), e11 = fast_exp2(s1[1]);
            float e12 = fast_exp2(s1[2]), e13 = fast_exp2(s1[3]);

            int A0 = pk_trunc(e00, e01);
            int A1 = pk_trunc(e02, e03);
            int B0 = pk_trunc(e10, e11);
            int B1 = pk_trunc(e12, e13);

            int w0a = __shfl(A0, base);  int w0b = __shfl(B0, base);
            int w1a = __shfl(A1, base);  int w1b = __shfl(B1, base);
            int w2a = __shfl(A0, base2); int w2b = __shfl(B0, base2);
            int w3a = __shfl(A1, base2); int w3b = __shfl(B1, base2);

            intx4 ptd;
            ptd[0] = hi ? w0b : w0a;
            ptd[1] = hi ? w1b : w1a;
            ptd[2] = hi ? w2b : w2a;
            ptd[3] = hi ? w3b : w3a;
            pt[f] = __builtin_bit_cast(short8, ptd);
        }

        #pragma unroll
        for (int f = 0; f < 4; ++f)
            accl[f] = __builtin_amdgcn_mfma_f32_16x16x32_bf16(ones, pt[f], accl[f], 0, 0, 0);

        #pragma unroll
        for (int ct = 0; ct < 4; ++ct)
            #pragma unroll
            for (int f = 0; f < 4; ++f)
                acc[f][ct] = __builtin_amdgcn_mfma_f32_16x16x32_bf16(vf[ct], pt[f], acc[f][ct], 0, 0, 0);
    }

    float lsum[4];
    #pragma unroll
    for (int f = 0; f < 4; ++f) lsum[f] = accl[f][0];

    // ---- reduction tree over key-quarters: (0+=1, 2+=3), then 0+=2 ----
    if (kh & 1) {
        const int s = kh >> 1;
        #pragma unroll
        for (int f = 0; f < 4; ++f)
            #pragma unroll
            for (int ct = 0; ct < 4; ++ct)
                #pragma unroll
                for (int r = 0; r < 4; ++r)
                    red[s][((f * 4 + ct) * 4 + r) * 64 + lane] = acc[f][ct][r];
        if (qd == 0)
            #pragma unroll
            for (int f = 0; f < 4; ++f) lred[s][f * 16 + l15] = lsum[f];
    }
    __syncthreads();
    if (!(kh & 1)) {
        const int s = kh >> 1;
        #pragma unroll
        for (int f = 0; f < 4; ++f) {
            #pragma unroll
            for (int ct = 0; ct < 4; ++ct)
                #pragma unroll
                for (int r = 0; r < 4; ++r)
                    acc[f][ct][r] += red[s][((f * 4 + ct) * 4 + r) * 64 + lane];
            lsum[f] += lred[s][f * 16 + l15];
        }
    }
    __syncthreads();
    if (kh == 2) {
        #pragma unroll
        for (int f = 0; f < 4; ++f)
            #pragma unroll
            for (int ct = 0; ct < 4; ++ct)
                #pragma unroll
                for (int r = 0; r < 4; ++r)
                    red[0][((f * 4 + ct) * 4 + r) * 64 + lane] = acc[f][ct][r];
        if (qd == 0)
            #pragma unroll
            for (int f = 0; f < 4; ++f) lred[0][f * 16 + l15] = lsum[f];
    }
    __syncthreads();
    if (kh == 0) {
        #pragma unroll
        for (int f = 0; f < 4; ++f) {
            #pragma unroll
            for (int ct = 0; ct < 4; ++ct)
                #pragma unroll
                for (int r = 0; r < 4; ++r)
                    acc[f][ct][r] += red[0][((f * 4 + ct) * 4 + r) * 64 + lane];
            lsum[f] += lred[0][f * 16 + l15];
        }
        #pragma unroll
        for (int f = 0; f < 4; ++f) {
            const float inv = 1.0f / lsum[f];
            ushort* dst = aoT + ((size_t)b * NN + q0 + f * 16 + l15) * CC + c0 + qd * 4;
            #pragma unroll
            for (int ct = 0; ct < 4; ++ct) {
                ushort4 h;
                h.x = f2bf(acc[f][ct][0] * inv);
                h.y = f2bf(acc[f][ct][1] * inv);
                h.z = f2bf(acc[f][ct][2] * inv);
                h.w = f2bf(acc[f][ct][3] * inv);
                *(ushort4*)(dst + ct * 16) = h;
            }
        }
    }
}

// ---------------------------------------------------------------------------
// Kernel 3: MFMA output projection + residual, high-TLP variant.
// Wave tile = 32m x 32n -> 4096 waves = 4/SIMD (was 2).  A-frags cast from
// fp32 Wp in-register; B-frags straight short8 loads from bf16 aoT (B,N,C).
// out = x + gamma*(Wp@ao + bp).
// ---------------------------------------------------------------------------
__global__ __launch_bounds__(256) void proj_mfma(
    const ushort* __restrict__ aoT, const float* __restrict__ Wp,
    const float* __restrict__ bp, const float* __restrict__ x,
    const float* __restrict__ gamma, float* __restrict__ out)
{
    const int t = threadIdx.x;
    const int wave = t >> 6;
    const int lane = t & 63;
    const int l15 = lane & 15;
    const int qd = lane >> 4;
    const int b = blockIdx.z;
    const int m0 = blockIdx.y * 32;
    const int n0 = blockIdx.x * 128 + wave * 32;

    floatx4 z = {0.f, 0.f, 0.f, 0.f};
    floatx4 acc[2][2];   // [fm][fn]
    acc[0][0] = z; acc[0][1] = z; acc[1][0] = z; acc[1][1] = z;

    const ushort* arow = aoT + ((size_t)b * NN + n0 + l15) * CC + qd * 8;
    const float* wrow = Wp + (size_t)(m0 + l15) * CC + qd * 8;

    #pragma unroll
    for (int k0 = 0; k0 < CC; k0 += 32) {
        short8 af[2], bf[2];
        #pragma unroll
        for (int f = 0; f < 2; ++f) {
            const float* p = wrow + (size_t)f * 16 * CC + k0;
            intx4 d;
            d[0] = pk_trunc(p[0], p[1]); d[1] = pk_trunc(p[2], p[3]);
            d[2] = pk_trunc(p[4], p[5]); d[3] = pk_trunc(p[6], p[7]);
            af[f] = __builtin_bit_cast(short8, d);
            bf[f] = *(const short8*)(arow + (size_t)f * 16 * CC + k0);
        }
        #pragma unroll
        for (int fm = 0; fm < 2; ++fm)
            #pragma unroll
            for (int fn = 0; fn < 2; ++fn)
                acc[fm][fn] = __builtin_amdgcn_mfma_f32_16x16x32_bf16(af[fm], bf[fn], acc[fm][fn], 0, 0, 0);
    }

    const float g = gamma[0];
    #pragma unroll
    for (int fm = 0; fm < 2; ++fm) {
        #pragma unroll
        for (int r = 0; r < 4; ++r) {
            int m = m0 + fm * 16 + qd * 4 + r;
            float bpv = bp[m];
            #pragma unroll
            for (int fn = 0; fn < 2; ++fn) {
                size_t addr = ((size_t)b * CC + m) * NN + n0 + fn * 16 + l15;
                out[addr] = fmaf(g, acc[fm][fn][r] + bpv, x[addr]);
            }
        }
    }
}

extern "C" void kernel_launch(void* const* d_in, const int* in_sizes, int n_in,
                              void* d_out, int out_size, void* d_ws, size_t ws_size,
                              hipStream_t stream)
{
    const float* x     = (const float*)d_in[0];
    const float* Wq    = (const float*)d_in[1];
    const float* bq    = (const float*)d_in[2];
    const float* Wk    = (const float*)d_in[3];
    const float* bk    = (const float*)d_in[4];
    const float* Wv    = (const float*)d_in[5];
    const float* bv    = (const float*)d_in[6];
    const float* Wp    = (const float*)d_in[7];
    const float* bp    = (const float*)d_in[8];
    const float* gamma = (const float*)d_in[9];
    float* out = (float*)d_out;

    ushort* qbw = (ushort*)d_ws;                        // B*N*32  bf16 = 1 MB
    ushort* kbw = qbw + (size_t)BB * NN * DD;           // B*N*32  bf16 = 1 MB
    ushort* vbw = kbw + (size_t)BB * NN * DD;           // B*C*N   bf16 = 8 MB
    ushort* aoT = vbw + (size_t)BB * CC * NN;           // B*N*C   bf16 = 8 MB

    qkv_mfma<<<dim3(NN / 128, 10, BB), 256, 0, stream>>>(x, Wq, bq, Wk, bk, Wv, bv, qbw, kbw, vbw);
    attn_mfma<<<dim3(8, 32, 4), 256, 0, stream>>>(qbw, kbw, vbw, aoT);
    proj_mfma<<<dim3(NN / 128, CC / 32, BB), 256, 0, stream>>>(aoT, Wp, bp, x, gamma, out);
}